// Round 6
// baseline (585.524 us; speedup 1.0000x reference)
//
#include <hip/hip_runtime.h>
#include <cfloat>

#define TOKENS 16384   // B*N
#define DDIM   2048
#define NEXP   128
#define KTOP   8
#define MB     32      // tokens per block (8 per wave)
#define KB     32      // k per LDS tile
#define NTILES (DDIM / KB)   // 64

// branchless sorted-insert into descending top-8 list.
// strict '>' => ties keep the earlier (lower) index, matching jax.lax.top_k.
__device__ __forceinline__ void insert8(float (&vals)[8], int (&idxs)[8], float v, int e) {
    bool c[8];
#pragma unroll
    for (int p = 0; p < 8; ++p) c[p] = v > vals[p];
#pragma unroll
    for (int p = 7; p >= 1; --p) {
        vals[p] = c[p] ? (c[p - 1] ? vals[p - 1] : v) : vals[p];
        idxs[p] = c[p] ? (c[p - 1] ? idxs[p - 1] : e) : idxs[p];
    }
    vals[0] = c[0] ? v : vals[0];
    idxs[0] = c[0] ? e : idxs[0];
}

// SGPR-x design: each wave owns 8 tokens -> x loads are wave-uniform ->
// s_load through the SMEM pipe (off both LDS and VMEM-VGPR paths); the FMA
// reads x as the one allowed SGPR operand. LDS holds only W (2 ds_read_b128
// per kq per wave). Per-CU pipe balance at 2 blocks/CU: LDS ~1920cy vs VALU
// ~2048cy per tile -> VALU-bound (R0 was LDS-bound at 576vs256 -> 44% cap).
// Per-logit FMA order (t,kq,x/y/z/w) identical to R0 -> bitwise-same logits.
__global__ __launch_bounds__(256, 1) void router_kernel(
    const float* __restrict__ x, const float* __restrict__ W,
    const float* __restrict__ b, float* __restrict__ out_gates,
    float* __restrict__ out_idx)
{
    __shared__ __align__(16) char smem[33280];
    float* ws0 = (float*)smem;                // [2][128*32] = 32768 B (GEMM)
    float* lg  = (float*)smem;                // [32][132]   = 16896 B (epilogue overlay)
    float* plv = (float*)(smem + 16896);      // [256][8] f32 = 8192 B
    int*   pli = (int*)(smem + 25088);        // [256][8] i32 = 8192 B

    const int tid  = threadIdx.x;
    const int lane = tid & 63;
    const int wid  = __builtin_amdgcn_readfirstlane(tid >> 6);  // wave 0..3 (uniform)
    const int tok0 = blockIdx.x * MB;

    // per-lane experts: e0 = lane, e1 = lane + 64
    const float bv0 = b[lane];
    const float bv1 = b[lane + 64];

    float acc[8][2];
#pragma unroll
    for (int i = 0; i < 8; ++i) { acc[i][0] = 0.0f; acc[i][1] = 0.0f; }

    const float4* W4 = (const float4*)W;
    // uniform x base for this wave's 8 tokens
    const float4* xu = (const float4*)x + (size_t)(tok0 + 8 * wid) * (DDIM / 4);

    // W staging: thread stages rows e = 32r + (tid>>3), slot q = tid&7,
    // XOR float4-slot swizzle -> 8 lanes per bank-quad on read AND write (optimal)
    const int wrow = tid >> 3, wq = tid & 7;
    float4 sw[4];

    // ---- prologue: stage W tile 0 ----
#pragma unroll
    for (int r = 0; r < 4; ++r)
        sw[r] = W4[(size_t)(32 * r + wrow) * (DDIM / 4) + wq];
#pragma unroll
    for (int r = 0; r < 4; ++r) {
        int e = 32 * r + wrow;
        *(float4*)&ws0[e * KB + 4 * (wq ^ (e & 7))] = sw[r];
    }
    __syncthreads();

    // x software pipeline: even kq reads xa, odd reads xb; prefetch one ahead.
    // All addresses wave-uniform -> s_load; values feed v_fmac as SGPR src.
    float4 xa[8], xb[8];
#pragma unroll
    for (int i = 0; i < 8; ++i) xa[i] = xu[i * (DDIM / 4)];

    // ---- main K loop ----
    for (int t = 0; t < NTILES; ++t) {
        const float* wsc = ws0 + (t & 1) * (NEXP * KB);
        const bool more = (t + 1) < NTILES;
        if (more) {
#pragma unroll
            for (int r = 0; r < 4; ++r)
                sw[r] = W4[(size_t)(32 * r + wrow) * (DDIM / 4) + (t + 1) * 8 + wq];
        }

#pragma unroll
        for (int kq = 0; kq < 8; ++kq) {
            // prefetch x for next kq (next K4 index; clamp keeps it in-bounds
            // on the very last iteration, value unused)
            const int nk  = t * 8 + kq + 1;
            const int nkc = nk < (DDIM / 4) ? nk : (DDIM / 4) - 1;
            if ((kq & 1) == 0) {
#pragma unroll
                for (int i = 0; i < 8; ++i) xb[i] = xu[i * (DDIM / 4) + nkc];
            } else {
#pragma unroll
                for (int i = 0; i < 8; ++i) xa[i] = xu[i * (DDIM / 4) + nkc];
            }

            // W fragments for this kq (only LDS traffic in the loop)
            const int slot = 4 * (kq ^ (lane & 7));
            const float4 wv0 = *(const float4*)&wsc[lane * KB + slot];
            const float4 wv1 = *(const float4*)&wsc[(lane + 64) * KB + slot];

            // strict k-ascending (t, kq, x/y/z/w) -> bit-identical to R0 logits
#pragma unroll
            for (int i = 0; i < 8; ++i) {
                const float4 xs = ((kq & 1) == 0) ? xa[i] : xb[i];
                acc[i][0] += xs.x * wv0.x;
                acc[i][0] += xs.y * wv0.y;
                acc[i][0] += xs.z * wv0.z;
                acc[i][0] += xs.w * wv0.w;
                acc[i][1] += xs.x * wv1.x;
                acc[i][1] += xs.y * wv1.y;
                acc[i][1] += xs.z * wv1.z;
                acc[i][1] += xs.w * wv1.w;
            }
        }

        if (more) {
            float* wsn = ws0 + ((t + 1) & 1) * (NEXP * KB);
#pragma unroll
            for (int r = 0; r < 4; ++r) {
                int e = 32 * r + wrow;
                *(float4*)&wsn[e * KB + 4 * (wq ^ (e & 7))] = sw[r];
            }
        }
        __syncthreads();
    }

    // ---- epilogue: logits -> LDS (overlay; W tiles dead after final barrier) ----
#pragma unroll
    for (int i = 0; i < 8; ++i) {
        int m = 8 * wid + i;
        lg[m * 132 + lane]      = acc[i][0] + bv0;
        lg[m * 132 + lane + 64] = acc[i][1] + bv1;
    }
    __syncthreads();

    // ---- partial top-8: 8 threads per token, 16 experts each ----
    {
        int tt = tid >> 3, p = tid & 7;
        float vals[8]; int idxs[8];
#pragma unroll
        for (int k = 0; k < 8; ++k) { vals[k] = -FLT_MAX; idxs[k] = 0; }
        const float* row = &lg[tt * 132 + p * 16];
#pragma unroll
        for (int q = 0; q < 16; ++q)
            insert8(vals, idxs, row[q], p * 16 + q);
#pragma unroll
        for (int k = 0; k < 8; ++k) {
            plv[tid * 8 + k] = vals[k];
            pli[tid * 8 + k] = idxs[k];
        }
    }
    __syncthreads();

    // ---- merge + softmax + index output (1 thread per token) ----
    float g[8]; int fidx[8];
    const bool active = (tid < MB);
    if (active) {
        float vals[8]; int idxs[8];
#pragma unroll
        for (int k = 0; k < 8; ++k) { vals[k] = -FLT_MAX; idxs[k] = 0; }
        for (int p = 0; p < 8; ++p) {
#pragma unroll
            for (int k = 0; k < 8; ++k)
                insert8(vals, idxs, plv[(tid * 8 + p) * 8 + k], pli[(tid * 8 + p) * 8 + k]);
        }
        float mx = vals[0];
        float s = 0.0f;
#pragma unroll
        for (int k = 0; k < 8; ++k) { g[k] = __expf(vals[k] - mx); s += g[k]; }
        float inv = 1.0f / s;
#pragma unroll
        for (int k = 0; k < 8; ++k) { g[k] *= inv; fidx[k] = idxs[k]; }
        // indices written as float values (whole out buffer is read back as f32)
#pragma unroll
        for (int k = 0; k < 8; ++k)
            out_idx[(size_t)(tok0 + tid) * KTOP + k] = (float)idxs[k];
    }
    // zero dense gate rows (merge no longer reads lg)
    for (int f = tid; f < MB * 132; f += 256) lg[f] = 0.0f;
    __syncthreads();

    if (active) {
#pragma unroll
        for (int k = 0; k < 8; ++k) lg[tid * 132 + fidx[k]] = g[k];
    }
    __syncthreads();

    // ---- coalesced dense copy-out ----
    for (int f = tid; f < MB * (NEXP / 4); f += 256) {
        int m = f >> 5, e4 = f & 31;
        float4 v = *(const float4*)&lg[m * 132 + e4 * 4];
        ((float4*)out_gates)[(size_t)(tok0 + m) * (NEXP / 4) + e4] = v;
    }
}

extern "C" void kernel_launch(void* const* d_in, const int* in_sizes, int n_in,
                              void* d_out, int out_size, void* d_ws, size_t ws_size,
                              hipStream_t stream) {
    const float* x = (const float*)d_in[0];   // [B,N,D] f32
    const float* W = (const float*)d_in[1];   // [E,D]   f32
    const float* b = (const float*)d_in[2];   // [E]     f32

    float* out_gates = (float*)d_out;                       // [B,N,E] f32
    float* out_idx   = out_gates + (size_t)TOKENS * NEXP;   // [B,N,K] as f32

    dim3 grid(TOKENS / MB);   // 512 blocks = 2 per CU
    dim3 block(256);
    router_kernel<<<grid, block, 0, stream>>>(x, W, b, out_gates, out_idx);
}

// Round 10
// 68.199 us; speedup vs baseline: 8.5856x; 8.5856x over previous
//
#include <hip/hip_runtime.h>
#include <cfloat>

#define TOKENS 16384   // B*N
#define DDIM   2048
#define NEXP   128
#define KTOP   8
#define MB     32      // tokens per block
#define CH     64      // k elements per chunk
#define NCH    (DDIM / CH)   // 32

typedef float    f32x4 __attribute__((ext_vector_type(4)));
typedef _Float16 f16x8 __attribute__((ext_vector_type(8)));

// W fragment tables in d_ws (rebuilt each launch):
//   WFH[((eb*NCH + c)*2 + ks)*64 + lane] : uint4 = 8 fp16  wh = fp16(w)
//   WFM = WFH + WFRAG_N                 : 8 fp16  wm = fp16((w - wh)*4096)
// Slot j of lane l holds k = c*64 + ks*32 + (l>>4)*8 + j, expert = eb*16 + (l&15).
// Same (l>>4,j)->k bijection used for the x tiles => correct dot products for
// ANY true hardware k-map (A/B symmetric layouts), evidenced by R6's near-miss
// (logits nearly right, failure was bf16 precision, not layout).
#define WFRAG_N (8 * NCH * 2 * 64)   // 32768 uint4 per table (512 KB)

__device__ __forceinline__ unsigned short f16bits(float f) {
    _Float16 h = (_Float16)f;                      // RNE
    return __builtin_bit_cast(unsigned short, h);
}
__device__ __forceinline__ float f16tof(unsigned short u) {
    return (float)__builtin_bit_cast(_Float16, u); // exact
}

__global__ __launch_bounds__(256, 1) void wfrag_kernel(
    const float* __restrict__ W, uint4* __restrict__ wf)
{
    int id   = blockIdx.x * 256 + threadIdx.x;   // 0..32767
    int lane = id & 63;
    int ks   = (id >> 6) & 1;
    int c    = (id >> 7) & (NCH - 1);
    int eb   = id >> 12;
    int e    = eb * 16 + (lane & 15);
    int k0   = c * CH + ks * 32 + (lane >> 4) * 8;
    const float* src = W + (size_t)e * DDIM + k0;
    unsigned hw[4], mw[4];
#pragma unroll
    for (int p = 0; p < 4; ++p) {
        float f0 = src[2 * p], f1 = src[2 * p + 1];
        unsigned short h0 = f16bits(f0), h1 = f16bits(f1);
        unsigned short m0 = f16bits((f0 - f16tof(h0)) * 4096.0f);
        unsigned short m1 = f16bits((f1 - f16tof(h1)) * 4096.0f);
        hw[p] = (unsigned)h0 | ((unsigned)h1 << 16);
        mw[p] = (unsigned)m0 | ((unsigned)m1 << 16);
    }
    wf[id]           = make_uint4(hw[0], hw[1], hw[2], hw[3]);
    wf[WFRAG_N + id] = make_uint4(mw[0], mw[1], mw[2], mw[3]);
}

// branchless sorted-insert into descending top-8 list.
// strict '>' => ties keep the earlier (lower) index, matching jax.lax.top_k.
__device__ __forceinline__ void insert8(float (&vals)[8], int (&idxs)[8], float v, int e) {
    bool c[8];
#pragma unroll
    for (int p = 0; p < 8; ++p) c[p] = v > vals[p];
#pragma unroll
    for (int p = 7; p >= 1; --p) {
        vals[p] = c[p] ? (c[p - 1] ? vals[p - 1] : v) : vals[p];
        idxs[p] = c[p] ? (c[p - 1] ? idxs[p - 1] : e) : idxs[p];
    }
    vals[0] = c[0] ? v : vals[0];
    idxs[0] = c[0] ? e : idxs[0];
}

// fp16-split MFMA router: logit = xh*wh + (xh*wm + xm*wh)/4096, residuals
// pre-scaled by 2^12 to dodge fp16 denormal flush. Total deviation from true
// fp32 ~3e-7 < R0's sequential-fp32 deviation (~1e-6) that passed 5 benches.
// Wave owns 32 tok x 32 exp (2 M-frags x 2 N-frags, 16x16x32 f16, 3 passes).
// x: global->reg->split->swizzled LDS h/m tiles. W: pre-split fragments from
// d_ws (L2-resident). x prefetch 2 chunks deep, W 1 deep, unroll-2 reg sets.
__global__ __launch_bounds__(256, 1) void router_kernel(
    const float* __restrict__ x, const uint4* __restrict__ wf,
    const float* __restrict__ b, float* __restrict__ out_gates,
    float* __restrict__ out_idx)
{
    // GEMM phase: xh dbuf [2][32*64]f16 @0,4096; xm dbuf @8192,12288 (16 KB)
    // Epilogue overlay: lg [32][132] f32 @0; plv @16896; pli @25088
    __shared__ __align__(16) char smem[33280];
    float* lg  = (float*)smem;
    float* plv = (float*)(smem + 16896);
    int*   pli = (int*)(smem + 25088);

    const int tid  = threadIdx.x;
    const int lane = tid & 63;
    const int wid  = tid >> 6;           // wave 0..3 -> experts [32w, 32w+32)
    const int tok0 = blockIdx.x * MB;

    const uint4* WFH = wf;
    const uint4* WFM = wf + WFRAG_N;
    const int eb0 = wid * 2;             // expert-blocks of 16: eb0, eb0+1

    f32x4 acc1[2][2], acc2[2][2];
#pragma unroll
    for (int mf = 0; mf < 2; ++mf)
#pragma unroll
        for (int nf = 0; nf < 2; ++nf) {
            acc1[mf][nf] = (f32x4){0.f, 0.f, 0.f, 0.f};
            acc2[mf][nf] = (f32x4){0.f, 0.f, 0.f, 0.f};
        }

    const float4* x4 = (const float4*)x;
    // x staging: thread r=0: row tid>>4, r=1: row 16+(tid>>4); float4-col tid&15
    const int xm0 = tid >> 4, xm1 = 16 + (tid >> 4), xq = tid & 15;
    const size_t xoff0 = (size_t)(tok0 + xm0) * (DDIM / 4) + xq;
    const size_t xoff1 = (size_t)(tok0 + xm1) * (DDIM / 4) + xq;
    // swizzled LDS byte offsets (16B-slot ^= row&7); 8 B (4 fp16) per write
    const int xb0 = xm0 * 128 + (((xq >> 1) ^ (xm0 & 7)) << 4) + (xq & 1) * 8;
    const int xb1 = xm1 * 128 + (((xq >> 1) ^ (xm1 & 7)) << 4) + (xq & 1) * 8;

    float4 sxA[2], sxB[2];
    uint4  wA[8], wB[8];   // [0..3]=wh (nf*2+ks), [4..7]=wm

    auto loadW = [&](int c, uint4 (&wreg)[8]) {
#pragma unroll
        for (int nf = 0; nf < 2; ++nf)
#pragma unroll
            for (int ks = 0; ks < 2; ++ks) {
                int idx = (((eb0 + nf) * NCH + c) * 2 + ks) * 64 + lane;
                wreg[nf * 2 + ks]     = WFH[idx];
                wreg[4 + nf * 2 + ks] = WFM[idx];
            }
    };
    auto convertX = [&](const float4 (&sx)[2], char* ldsDst) {
#pragma unroll
        for (int r = 0; r < 2; ++r) {
            float4 v = sx[r];
            unsigned short h0 = f16bits(v.x), h1 = f16bits(v.y);
            unsigned short h2 = f16bits(v.z), h3 = f16bits(v.w);
            unsigned short m0 = f16bits((v.x - f16tof(h0)) * 4096.0f);
            unsigned short m1 = f16bits((v.y - f16tof(h1)) * 4096.0f);
            unsigned short m2 = f16bits((v.z - f16tof(h2)) * 4096.0f);
            unsigned short m3 = f16bits((v.w - f16tof(h3)) * 4096.0f);
            uint2 hv = make_uint2((unsigned)h0 | ((unsigned)h1 << 16),
                                  (unsigned)h2 | ((unsigned)h3 << 16));
            uint2 mv = make_uint2((unsigned)m0 | ((unsigned)m1 << 16),
                                  (unsigned)m2 | ((unsigned)m3 << 16));
            int byteoff = r ? xb1 : xb0;
            *(uint2*)(ldsDst + byteoff)        = hv;
            *(uint2*)(ldsDst + 8192 + byteoff) = mv;
        }
    };

    // ---- prologue ----
    sxA[0] = x4[xoff0];  sxA[1] = x4[xoff1];                   // x(0)
    loadW(0, wA);                                              // W(0)
    sxB[0] = x4[xoff0 + 16];  sxB[1] = x4[xoff1 + 16];         // x(1)
    convertX(sxA, smem);                                       // -> buf0
    __syncthreads();

    auto step = [&](int c, uint4 (&wCur)[8], uint4 (&wNext)[8],
                    float4 (&sxCur)[2], float4 (&sxNext)[2],
                    char* ldsCur, char* ldsNext) {
        if (c + 2 < NCH) {   // issue x(c+2)
            sxNext[0] = x4[xoff0 + (size_t)(c + 2) * 16];
            sxNext[1] = x4[xoff1 + (size_t)(c + 2) * 16];
        }
        if (c + 1 < NCH) loadW(c + 1, wNext);   // issue W(c+1)

        // compute chunk c: 8 ds_read_b128 + 24 MFMAs
#pragma unroll
        for (int ks = 0; ks < 2; ++ks) {
            f16x8 ah[2], am[2];
#pragma unroll
            for (int mf = 0; mf < 2; ++mf) {
                int row = 16 * mf + (lane & 15);
                int byteoff = row * 128 +
                    ((((ks << 2) | (lane >> 4)) ^ (row & 7)) << 4);
                ah[mf] = *(const f16x8*)(ldsCur + byteoff);
                am[mf] = *(const f16x8*)(ldsCur + 8192 + byteoff);
            }
#pragma unroll
            for (int mf = 0; mf < 2; ++mf)
#pragma unroll
                for (int nf = 0; nf < 2; ++nf) {
                    f16x8 wh = __builtin_bit_cast(f16x8, wCur[nf * 2 + ks]);
                    f16x8 wm = __builtin_bit_cast(f16x8, wCur[4 + nf * 2 + ks]);
                    acc1[mf][nf] = __builtin_amdgcn_mfma_f32_16x16x32_f16(
                        ah[mf], wh, acc1[mf][nf], 0, 0, 0);
                    acc2[mf][nf] = __builtin_amdgcn_mfma_f32_16x16x32_f16(
                        ah[mf], wm, acc2[mf][nf], 0, 0, 0);
                    acc2[mf][nf] = __builtin_amdgcn_mfma_f32_16x16x32_f16(
                        am[mf], wh, acc2[mf][nf], 0, 0, 0);
                }
        }

        if (c + 1 < NCH) convertX(sxCur, ldsNext);   // x(c+1) -> other buf
        __syncthreads();
    };

    for (int cc = 0; cc < NCH; cc += 2) {
        step(cc,     wA, wB, sxB, sxA, smem,        smem + 4096);
        step(cc + 1, wB, wA, sxA, sxB, smem + 4096, smem);
    }

    // ---- epilogue: logits -> LDS (C/D: col=lane&15 -> expert,
    // row=(lane>>4)*4+reg -> token; m89-verified, dtype-independent) ----
    const float bb0 = b[wid * 32 + (lane & 15)];
    const float bb1 = b[wid * 32 + 16 + (lane & 15)];
#pragma unroll
    for (int mf = 0; mf < 2; ++mf)
#pragma unroll
        for (int nf = 0; nf < 2; ++nf) {
            float bb = nf ? bb1 : bb0;
#pragma unroll
            for (int r = 0; r < 4; ++r) {
                int t = 16 * mf + (lane >> 4) * 4 + r;
                int e = wid * 32 + 16 * nf + (lane & 15);
                lg[t * 132 + e] =
                    fmaf(acc2[mf][nf][r], 0.000244140625f, acc1[mf][nf][r]) + bb;
            }
        }
    __syncthreads();

    // ---- partial top-8: 8 threads per token, 16 experts each ----
    {
        int tt = tid >> 3, p = tid & 7;
        float vals[8]; int idxs[8];
#pragma unroll
        for (int k = 0; k < 8; ++k) { vals[k] = -FLT_MAX; idxs[k] = 0; }
        const float* row = &lg[tt * 132 + p * 16];
#pragma unroll
        for (int q = 0; q < 16; ++q)
            insert8(vals, idxs, row[q], p * 16 + q);
#pragma unroll
        for (int k = 0; k < 8; ++k) {
            plv[tid * 8 + k] = vals[k];
            pli[tid * 8 + k] = idxs[k];
        }
    }
    __syncthreads();

    // ---- merge + softmax + index output (1 thread per token) ----
    float g[8]; int fidx[8];
    const bool active = (tid < MB);
    if (active) {
        float vals[8]; int idxs[8];
#pragma unroll
        for (int k = 0; k < 8; ++k) { vals[k] = -FLT_MAX; idxs[k] = 0; }
        for (int p = 0; p < 8; ++p) {
#pragma unroll
            for (int k = 0; k < 8; ++k)
                insert8(vals, idxs, plv[(tid * 8 + p) * 8 + k], pli[(tid * 8 + p) * 8 + k]);
        }
        float mx = vals[0];
        float s = 0.0f;
#pragma unroll
        for (int k = 0; k < 8; ++k) { g[k] = __expf(vals[k] - mx); s += g[k]; }
        float inv = 1.0f / s;
#pragma unroll
        for (int k = 0; k < 8; ++k) { g[k] *= inv; fidx[k] = idxs[k]; }
        // indices written as float values (whole out buffer is read back as f32)
#pragma unroll
        for (int k = 0; k < 8; ++k)
            out_idx[(size_t)(tok0 + tid) * KTOP + k] = (float)idxs[k];
    }
    // zero dense gate rows (merge no longer reads lg)
    for (int f = tid; f < MB * 132; f += 256) lg[f] = 0.0f;
    __syncthreads();

    if (active) {
#pragma unroll
        for (int k = 0; k < 8; ++k) lg[tid * 132 + fidx[k]] = g[k];
    }
    __syncthreads();

    // ---- coalesced dense copy-out ----
    for (int f = tid; f < MB * (NEXP / 4); f += 256) {
        int m = f >> 5, e4 = f & 31;
        float4 v = *(const float4*)&lg[m * 132 + e4 * 4];
        ((float4*)out_gates)[(size_t)(tok0 + m) * (NEXP / 4) + e4] = v;
    }
}

extern "C" void kernel_launch(void* const* d_in, const int* in_sizes, int n_in,
                              void* d_out, int out_size, void* d_ws, size_t ws_size,
                              hipStream_t stream) {
    const float* x = (const float*)d_in[0];   // [B,N,D] f32
    const float* W = (const float*)d_in[1];   // [E,D]   f32
    const float* b = (const float*)d_in[2];   // [E]     f32

    float* out_gates = (float*)d_out;                       // [B,N,E] f32
    float* out_idx   = out_gates + (size_t)TOKENS * NEXP;   // [B,N,K] as f32

    uint4* wf = (uint4*)d_ws;   // 1 MB: W fp16 h/m fragment tables

    wfrag_kernel<<<dim3(WFRAG_N / 256), dim3(256), 0, stream>>>(W, wf);
    router_kernel<<<dim3(TOKENS / MB), dim3(256), 0, stream>>>(x, wf, b, out_gates, out_idx);
}

// Round 11
// 65.710 us; speedup vs baseline: 8.9107x; 1.0379x over previous
//
#include <hip/hip_runtime.h>
#include <cfloat>

#define TOKENS 16384   // B*N
#define DDIM   2048
#define NEXP   128
#define KTOP   8
#define MB     32      // tokens per block
#define CH     64      // k elements per chunk
#define NCH    (DDIM / CH)   // 32
#define NTHR   512     // 8 waves/block -> 16 waves/CU at 2 blocks/CU

typedef float    f32x4 __attribute__((ext_vector_type(4)));
typedef _Float16 f16x8 __attribute__((ext_vector_type(8)));

// W fragment tables in d_ws (rebuilt each launch):
//   WFH[((eb*NCH + c)*2 + ks)*64 + lane] : uint4 = 8 fp16  wh = fp16(w)
//   WFM = WFH + WFRAG_N                 : 8 fp16  wm = fp16((w - wh)*4096)
// Slot j of lane l holds k = c*64 + ks*32 + (l>>4)*8 + j, expert = eb*16 + (l&15).
#define WFRAG_N (8 * NCH * 2 * 64)   // 32768 uint4 per table (512 KB)

__device__ __forceinline__ unsigned short f16bits(float f) {
    _Float16 h = (_Float16)f;                      // RNE
    return __builtin_bit_cast(unsigned short, h);
}
__device__ __forceinline__ float f16tof(unsigned short u) {
    return (float)__builtin_bit_cast(_Float16, u); // exact
}

__global__ __launch_bounds__(256, 1) void wfrag_kernel(
    const float* __restrict__ W, uint4* __restrict__ wf)
{
    int id   = blockIdx.x * 256 + threadIdx.x;   // 0..32767
    int lane = id & 63;
    int ks   = (id >> 6) & 1;
    int c    = (id >> 7) & (NCH - 1);
    int eb   = id >> 12;
    int e    = eb * 16 + (lane & 15);
    int k0   = c * CH + ks * 32 + (lane >> 4) * 8;
    const float* src = W + (size_t)e * DDIM + k0;
    unsigned hw[4], mw[4];
#pragma unroll
    for (int p = 0; p < 4; ++p) {
        float f0 = src[2 * p], f1 = src[2 * p + 1];
        unsigned short h0 = f16bits(f0), h1 = f16bits(f1);
        unsigned short m0 = f16bits((f0 - f16tof(h0)) * 4096.0f);
        unsigned short m1 = f16bits((f1 - f16tof(h1)) * 4096.0f);
        hw[p] = (unsigned)h0 | ((unsigned)h1 << 16);
        mw[p] = (unsigned)m0 | ((unsigned)m1 << 16);
    }
    wf[id]           = make_uint4(hw[0], hw[1], hw[2], hw[3]);
    wf[WFRAG_N + id] = make_uint4(mw[0], mw[1], mw[2], mw[3]);
}

// branchless sorted-insert into descending top-8 list.
// strict '>' => ties keep the earlier (lower) index, matching jax.lax.top_k.
__device__ __forceinline__ void insert8(float (&vals)[8], int (&idxs)[8], float v, int e) {
    bool c[8];
#pragma unroll
    for (int p = 0; p < 8; ++p) c[p] = v > vals[p];
#pragma unroll
    for (int p = 7; p >= 1; --p) {
        vals[p] = c[p] ? (c[p - 1] ? vals[p - 1] : v) : vals[p];
        idxs[p] = c[p] ? (c[p - 1] ? idxs[p - 1] : e) : idxs[p];
    }
    vals[0] = c[0] ? v : vals[0];
    idxs[0] = c[0] ? e : idxs[0];
}

// fp16-split MFMA router, 8-wave blocks (R10 passed at 68us with 2 blocks/CU
// = 8 waves/CU; nothing saturated -> latency-bound). This round: 512 threads,
// wave owns 32 tok x 16 exp -> 16 waves/CU at identical W/x traffic. Per-logit
// arithmetic sequence (chunk -> ks order, 3 passes, fmaf merge) unchanged ->
// logits bit-identical to R10 -> indices identical.
__global__ __launch_bounds__(NTHR, 1) void router_kernel(
    const float* __restrict__ x, const uint4* __restrict__ wf,
    const float* __restrict__ b, float* __restrict__ out_gates,
    float* __restrict__ out_idx)
{
    // GEMM phase: xh dbuf @0,4096; xm dbuf @8192,12288 (16 KB)
    // Epilogue overlay: lg [32][132] f32 @0; plv @16896; pli @25088
    __shared__ __align__(16) char smem[33280];
    float* lg  = (float*)smem;
    float* plv = (float*)(smem + 16896);
    int*   pli = (int*)(smem + 25088);

    const int tid  = threadIdx.x;
    const int lane = tid & 63;
    const int wid  = tid >> 6;           // wave 0..7 -> expert-block eb = wid
    const int tok0 = blockIdx.x * MB;

    const uint4* WFH = wf;
    const uint4* WFM = wf + WFRAG_N;

    f32x4 acc1[2], acc2[2];              // [mf]
#pragma unroll
    for (int mf = 0; mf < 2; ++mf) {
        acc1[mf] = (f32x4){0.f, 0.f, 0.f, 0.f};
        acc2[mf] = (f32x4){0.f, 0.f, 0.f, 0.f};
    }

    const float4* x4 = (const float4*)x;
    // x staging: 512 threads stage 32 rows x 16 float4-cols (1 per thread)
    const int xm = tid >> 4, xq = tid & 15;
    const size_t xoff = (size_t)(tok0 + xm) * (DDIM / 4) + xq;
    // swizzled LDS byte offset (16B-slot ^= row&7); 8 B (4 fp16) per write
    const int xb = xm * 128 + (((xq >> 1) ^ (xm & 7)) << 4) + (xq & 1) * 8;

    float4 sxA, sxB;
    uint4  wA[4], wB[4];   // [0..1]=wh (ks), [2..3]=wm (ks)

    auto loadW = [&](int c, uint4 (&wreg)[4]) {
#pragma unroll
        for (int ks = 0; ks < 2; ++ks) {
            int idx = ((wid * NCH + c) * 2 + ks) * 64 + lane;
            wreg[ks]     = WFH[idx];
            wreg[2 + ks] = WFM[idx];
        }
    };
    auto convertX = [&](const float4& v, char* ldsDst) {
        unsigned short h0 = f16bits(v.x), h1 = f16bits(v.y);
        unsigned short h2 = f16bits(v.z), h3 = f16bits(v.w);
        unsigned short m0 = f16bits((v.x - f16tof(h0)) * 4096.0f);
        unsigned short m1 = f16bits((v.y - f16tof(h1)) * 4096.0f);
        unsigned short m2 = f16bits((v.z - f16tof(h2)) * 4096.0f);
        unsigned short m3 = f16bits((v.w - f16tof(h3)) * 4096.0f);
        uint2 hv = make_uint2((unsigned)h0 | ((unsigned)h1 << 16),
                              (unsigned)h2 | ((unsigned)h3 << 16));
        uint2 mv = make_uint2((unsigned)m0 | ((unsigned)m1 << 16),
                              (unsigned)m2 | ((unsigned)m3 << 16));
        *(uint2*)(ldsDst + xb)        = hv;
        *(uint2*)(ldsDst + 8192 + xb) = mv;
    };

    // ---- prologue ----
    sxA = x4[xoff];                 // x(0)
    loadW(0, wA);                   // W(0)
    sxB = x4[xoff + 16];            // x(1)
    convertX(sxA, smem);            // -> buf0
    __syncthreads();

    auto step = [&](int c, uint4 (&wCur)[4], uint4 (&wNext)[4],
                    float4& sxCur, float4& sxNext,
                    char* ldsCur, char* ldsNext) {
        if (c + 2 < NCH)                     // issue x(c+2)
            sxNext = x4[xoff + (size_t)(c + 2) * 16];
        if (c + 1 < NCH) loadW(c + 1, wNext);   // issue W(c+1)

        // compute chunk c: 8 ds_read_b128 + 12 MFMAs
#pragma unroll
        for (int ks = 0; ks < 2; ++ks) {
            f16x8 ah[2], am[2];
#pragma unroll
            for (int mf = 0; mf < 2; ++mf) {
                int row = 16 * mf + (lane & 15);
                int byteoff = row * 128 +
                    ((((ks << 2) | (lane >> 4)) ^ (row & 7)) << 4);
                ah[mf] = *(const f16x8*)(ldsCur + byteoff);
                am[mf] = *(const f16x8*)(ldsCur + 8192 + byteoff);
            }
            f16x8 wh = __builtin_bit_cast(f16x8, wCur[ks]);
            f16x8 wm = __builtin_bit_cast(f16x8, wCur[2 + ks]);
#pragma unroll
            for (int mf = 0; mf < 2; ++mf) {
                acc1[mf] = __builtin_amdgcn_mfma_f32_16x16x32_f16(
                    ah[mf], wh, acc1[mf], 0, 0, 0);
                acc2[mf] = __builtin_amdgcn_mfma_f32_16x16x32_f16(
                    ah[mf], wm, acc2[mf], 0, 0, 0);
                acc2[mf] = __builtin_amdgcn_mfma_f32_16x16x32_f16(
                    am[mf], wh, acc2[mf], 0, 0, 0);
            }
        }

        if (c + 1 < NCH) convertX(sxCur, ldsNext);   // x(c+1) -> other buf
        __syncthreads();
    };

    for (int cc = 0; cc < NCH; cc += 2) {
        step(cc,     wA, wB, sxB, sxA, smem,        smem + 4096);
        step(cc + 1, wB, wA, sxA, sxB, smem + 4096, smem);
    }

    // ---- epilogue: logits -> LDS (C/D: col=lane&15 -> expert,
    // row=(lane>>4)*4+reg -> token) ----
    const float bb = b[wid * 16 + (lane & 15)];
#pragma unroll
    for (int mf = 0; mf < 2; ++mf)
#pragma unroll
        for (int r = 0; r < 4; ++r) {
            int t = 16 * mf + (lane >> 4) * 4 + r;
            int e = wid * 16 + (lane & 15);
            lg[t * 132 + e] =
                fmaf(acc2[mf][r], 0.000244140625f, acc1[mf][r]) + bb;
        }
    __syncthreads();

    // ---- partial top-8: first 256 threads, 8 per token, 16 experts each ----
    if (tid < 256) {
        int tt = tid >> 3, p = tid & 7;
        float vals[8]; int idxs[8];
#pragma unroll
        for (int k = 0; k < 8; ++k) { vals[k] = -FLT_MAX; idxs[k] = 0; }
        const float* row = &lg[tt * 132 + p * 16];
#pragma unroll
        for (int q = 0; q < 16; ++q)
            insert8(vals, idxs, row[q], p * 16 + q);
#pragma unroll
        for (int k = 0; k < 8; ++k) {
            plv[tid * 8 + k] = vals[k];
            pli[tid * 8 + k] = idxs[k];
        }
    }
    __syncthreads();

    // ---- merge + softmax + index output (1 thread per token) ----
    float g[8]; int fidx[8];
    const bool active = (tid < MB);
    if (active) {
        float vals[8]; int idxs[8];
#pragma unroll
        for (int k = 0; k < 8; ++k) { vals[k] = -FLT_MAX; idxs[k] = 0; }
        for (int p = 0; p < 8; ++p) {
#pragma unroll
            for (int k = 0; k < 8; ++k)
                insert8(vals, idxs, plv[(tid * 8 + p) * 8 + k], pli[(tid * 8 + p) * 8 + k]);
        }
        float mx = vals[0];
        float s = 0.0f;
#pragma unroll
        for (int k = 0; k < 8; ++k) { g[k] = __expf(vals[k] - mx); s += g[k]; }
        float inv = 1.0f / s;
#pragma unroll
        for (int k = 0; k < 8; ++k) { g[k] *= inv; fidx[k] = idxs[k]; }
        // indices written as float values (whole out buffer is read back as f32)
#pragma unroll
        for (int k = 0; k < 8; ++k)
            out_idx[(size_t)(tok0 + tid) * KTOP + k] = (float)idxs[k];
    }
    // zero dense gate rows (merge no longer reads lg)
    for (int f = tid; f < MB * 132; f += NTHR) lg[f] = 0.0f;
    __syncthreads();

    if (active) {
#pragma unroll
        for (int k = 0; k < 8; ++k) lg[tid * 132 + fidx[k]] = g[k];
    }
    __syncthreads();

    // ---- coalesced dense copy-out ----
    for (int f = tid; f < MB * (NEXP / 4); f += NTHR) {
        int m = f >> 5, e4 = f & 31;
        float4 v = *(const float4*)&lg[m * 132 + e4 * 4];
        ((float4*)out_gates)[(size_t)(tok0 + m) * (NEXP / 4) + e4] = v;
    }
}

extern "C" void kernel_launch(void* const* d_in, const int* in_sizes, int n_in,
                              void* d_out, int out_size, void* d_ws, size_t ws_size,
                              hipStream_t stream) {
    const float* x = (const float*)d_in[0];   // [B,N,D] f32
    const float* W = (const float*)d_in[1];   // [E,D]   f32
    const float* b = (const float*)d_in[2];   // [E]     f32

    float* out_gates = (float*)d_out;                       // [B,N,E] f32
    float* out_idx   = out_gates + (size_t)TOKENS * NEXP;   // [B,N,K] as f32

    uint4* wf = (uint4*)d_ws;   // 1 MB: W fp16 h/m fragment tables

    wfrag_kernel<<<dim3(WFRAG_N / 256), dim3(256), 0, stream>>>(W, wf);
    router_kernel<<<dim3(TOKENS / MB), dim3(NTHR), 0, stream>>>(x, wf, b, out_gates, out_idx);
}

// Round 12
// 62.159 us; speedup vs baseline: 9.4197x; 1.0571x over previous
//
#include <hip/hip_runtime.h>
#include <cfloat>

#define TOKENS 16384   // B*N
#define DDIM   2048
#define NEXP   128
#define KTOP   8
#define MB     64      // tokens per block
#define CH     64      // k elements per chunk
#define NCH    (DDIM / CH)   // 32
#define NTHR   512     // 8 waves/block, grid 256 -> 1 block/CU

typedef float    f32x4 __attribute__((ext_vector_type(4)));
typedef _Float16 f16x8 __attribute__((ext_vector_type(8)));

// W fragment tables in d_ws (rebuilt each launch):
//   WFH[((eb*NCH + c)*2 + ks)*64 + lane] : uint4 = 8 fp16  wh = fp16(w)
//   WFM = WFH + WFRAG_N                 : 8 fp16  wm = fp16((w - wh)*4096)
// Slot j of lane l holds k = c*64 + ks*32 + (l>>4)*8 + j, expert = eb*16 + (l&15).
#define WFRAG_N (8 * NCH * 2 * 64)   // 32768 uint4 per table (512 KB)

__device__ __forceinline__ unsigned short f16bits(float f) {
    _Float16 h = (_Float16)f;                      // RNE
    return __builtin_bit_cast(unsigned short, h);
}
__device__ __forceinline__ float f16tof(unsigned short u) {
    return (float)__builtin_bit_cast(_Float16, u); // exact
}

__global__ __launch_bounds__(256, 1) void wfrag_kernel(
    const float* __restrict__ W, uint4* __restrict__ wf)
{
    int id   = blockIdx.x * 256 + threadIdx.x;   // 0..32767
    int lane = id & 63;
    int ks   = (id >> 6) & 1;
    int c    = (id >> 7) & (NCH - 1);
    int eb   = id >> 12;
    int e    = eb * 16 + (lane & 15);
    int k0   = c * CH + ks * 32 + (lane >> 4) * 8;
    const float* src = W + (size_t)e * DDIM + k0;
    unsigned hw[4], mw[4];
#pragma unroll
    for (int p = 0; p < 4; ++p) {
        float f0 = src[2 * p], f1 = src[2 * p + 1];
        unsigned short h0 = f16bits(f0), h1 = f16bits(f1);
        unsigned short m0 = f16bits((f0 - f16tof(h0)) * 4096.0f);
        unsigned short m1 = f16bits((f1 - f16tof(h1)) * 4096.0f);
        hw[p] = (unsigned)h0 | ((unsigned)h1 << 16);
        mw[p] = (unsigned)m0 | ((unsigned)m1 << 16);
    }
    wf[id]           = make_uint4(hw[0], hw[1], hw[2], hw[3]);
    wf[WFRAG_N + id] = make_uint4(mw[0], mw[1], mw[2], mw[3]);
}

// branchless sorted-insert into descending top-8 list.
// strict '>' => ties keep the earlier (lower) index, matching jax.lax.top_k.
__device__ __forceinline__ void insert8(float (&vals)[8], int (&idxs)[8], float v, int e) {
    bool c[8];
#pragma unroll
    for (int p = 0; p < 8; ++p) c[p] = v > vals[p];
#pragma unroll
    for (int p = 7; p >= 1; --p) {
        vals[p] = c[p] ? (c[p - 1] ? vals[p - 1] : v) : vals[p];
        idxs[p] = c[p] ? (c[p - 1] ? idxs[p - 1] : e) : idxs[p];
    }
    vals[0] = c[0] ? v : vals[0];
    idxs[0] = c[0] ? e : idxs[0];
}

// fp16-split MFMA router, MB=64 (R10/R11 proved wave-count insensitivity ->
// the constraint is per-CU shared resources; doubling tokens/block halves
// per-token LDS-unit load, VMEM instr count (80->48/chunk/CU), W L2 traffic
// (512->256 MB), and barrier count). Wave owns 64 tok x 16 exp (4 M-frags).
// Per-logit accumulation sequence (chunk -> ks -> 3-pass, fmaf merge)
// unchanged -> logits bit-identical to R10/R11 -> indices identical.
__global__ __launch_bounds__(NTHR, 1) void router_kernel(
    const float* __restrict__ x, const uint4* __restrict__ wf,
    const float* __restrict__ b, float* __restrict__ out_gates,
    float* __restrict__ out_idx)
{
    // GEMM phase: xh dbuf @0,8192; xm dbuf @16384,24576 (32 KB total)
    // Epilogue overlay: lg [64][132] f32 @0 (33792); plv @33792; pli @50176
    __shared__ __align__(16) char smem[66560];
    float* lg  = (float*)smem;
    float* plv = (float*)(smem + 33792);
    int*   pli = (int*)(smem + 50176);

    const int tid  = threadIdx.x;
    const int lane = tid & 63;
    const int wid  = tid >> 6;           // wave 0..7 -> expert-block eb = wid
    const int tok0 = blockIdx.x * MB;

    const uint4* WFH = wf;
    const uint4* WFM = wf + WFRAG_N;

    f32x4 acc1[4], acc2[4];              // [mf] -> tokens 16*mf..16*mf+15
#pragma unroll
    for (int mf = 0; mf < 4; ++mf) {
        acc1[mf] = (f32x4){0.f, 0.f, 0.f, 0.f};
        acc2[mf] = (f32x4){0.f, 0.f, 0.f, 0.f};
    }

    const float4* x4 = (const float4*)x;
    // x staging: 512 threads stage 64 rows x 16 float4-cols (2 per thread)
    const int xr0 = tid >> 4, xr1 = 32 + (tid >> 4), xq = tid & 15;
    const size_t xoff0 = (size_t)(tok0 + xr0) * (DDIM / 4) + xq;
    const size_t xoff1 = (size_t)(tok0 + xr1) * (DDIM / 4) + xq;
    // swizzled LDS byte offsets (16B-slot ^= row&7); 8 B (4 fp16) per write
    const int xb0 = xr0 * 128 + (((xq >> 1) ^ (xr0 & 7)) << 4) + (xq & 1) * 8;
    const int xb1 = xr1 * 128 + (((xq >> 1) ^ (xr1 & 7)) << 4) + (xq & 1) * 8;

    float4 sxA[2], sxB[2];
    uint4  wA[4], wB[4];   // [0..1]=wh (ks), [2..3]=wm (ks)

    auto loadW = [&](int c, uint4 (&wreg)[4]) {
#pragma unroll
        for (int ks = 0; ks < 2; ++ks) {
            int idx = ((wid * NCH + c) * 2 + ks) * 64 + lane;
            wreg[ks]     = WFH[idx];
            wreg[2 + ks] = WFM[idx];
        }
    };
    auto convertX = [&](const float4 (&sx)[2], char* ldsDst) {
#pragma unroll
        for (int r = 0; r < 2; ++r) {
            const float4 v = sx[r];
            unsigned short h0 = f16bits(v.x), h1 = f16bits(v.y);
            unsigned short h2 = f16bits(v.z), h3 = f16bits(v.w);
            unsigned short m0 = f16bits((v.x - f16tof(h0)) * 4096.0f);
            unsigned short m1 = f16bits((v.y - f16tof(h1)) * 4096.0f);
            unsigned short m2 = f16bits((v.z - f16tof(h2)) * 4096.0f);
            unsigned short m3 = f16bits((v.w - f16tof(h3)) * 4096.0f);
            uint2 hv = make_uint2((unsigned)h0 | ((unsigned)h1 << 16),
                                  (unsigned)h2 | ((unsigned)h3 << 16));
            uint2 mv = make_uint2((unsigned)m0 | ((unsigned)m1 << 16),
                                  (unsigned)m2 | ((unsigned)m3 << 16));
            const int byteoff = r ? xb1 : xb0;
            *(uint2*)(ldsDst + byteoff)         = hv;
            *(uint2*)(ldsDst + 16384 + byteoff) = mv;
        }
    };

    // ---- prologue ----
    sxA[0] = x4[xoff0];  sxA[1] = x4[xoff1];          // x(0)
    loadW(0, wA);                                     // W(0)
    sxB[0] = x4[xoff0 + 16];  sxB[1] = x4[xoff1 + 16];// x(1)
    convertX(sxA, smem);                              // -> buf0
    __syncthreads();

    auto step = [&](int c, uint4 (&wCur)[4], uint4 (&wNext)[4],
                    float4 (&sxCur)[2], float4 (&sxNext)[2],
                    char* ldsCur, char* ldsNext) {
        if (c + 2 < NCH) {                   // issue x(c+2)
            sxNext[0] = x4[xoff0 + (size_t)(c + 2) * 16];
            sxNext[1] = x4[xoff1 + (size_t)(c + 2) * 16];
        }
        if (c + 1 < NCH) loadW(c + 1, wNext);   // issue W(c+1)

        // compute chunk c: 16 ds_read_b128 + 24 MFMAs per wave
#pragma unroll
        for (int ks = 0; ks < 2; ++ks) {
            f16x8 ah[4], am[4];
#pragma unroll
            for (int mf = 0; mf < 4; ++mf) {
                int row = 16 * mf + (lane & 15);
                int byteoff = row * 128 +
                    ((((ks << 2) | (lane >> 4)) ^ (row & 7)) << 4);
                ah[mf] = *(const f16x8*)(ldsCur + byteoff);
                am[mf] = *(const f16x8*)(ldsCur + 16384 + byteoff);
            }
            f16x8 wh = __builtin_bit_cast(f16x8, wCur[ks]);
            f16x8 wm = __builtin_bit_cast(f16x8, wCur[2 + ks]);
#pragma unroll
            for (int mf = 0; mf < 4; ++mf) {
                acc1[mf] = __builtin_amdgcn_mfma_f32_16x16x32_f16(
                    ah[mf], wh, acc1[mf], 0, 0, 0);
                acc2[mf] = __builtin_amdgcn_mfma_f32_16x16x32_f16(
                    ah[mf], wm, acc2[mf], 0, 0, 0);
                acc2[mf] = __builtin_amdgcn_mfma_f32_16x16x32_f16(
                    am[mf], wh, acc2[mf], 0, 0, 0);
            }
        }

        if (c + 1 < NCH) convertX(sxCur, ldsNext);   // x(c+1) -> other buf
        __syncthreads();
    };

    for (int cc = 0; cc < NCH; cc += 2) {
        step(cc,     wA, wB, sxB, sxA, smem,        smem + 8192);
        step(cc + 1, wB, wA, sxA, sxB, smem + 8192, smem);
    }

    // ---- epilogue: logits -> LDS (C/D: col=lane&15 -> expert,
    // row=(lane>>4)*4+reg -> token) ----
    const float bb = b[wid * 16 + (lane & 15)];
#pragma unroll
    for (int mf = 0; mf < 4; ++mf)
#pragma unroll
        for (int r = 0; r < 4; ++r) {
            int t = 16 * mf + (lane >> 4) * 4 + r;
            int e = wid * 16 + (lane & 15);
            lg[t * 132 + e] =
                fmaf(acc2[mf][r], 0.000244140625f, acc1[mf][r]) + bb;
        }
    __syncthreads();

    // ---- partial top-8: 8 threads per token, 16 experts each ----
    {
        int tt = tid >> 3, p = tid & 7;
        float vals[8]; int idxs[8];
#pragma unroll
        for (int k = 0; k < 8; ++k) { vals[k] = -FLT_MAX; idxs[k] = 0; }
        const float* row = &lg[tt * 132 + p * 16];
#pragma unroll
        for (int q = 0; q < 16; ++q)
            insert8(vals, idxs, row[q], p * 16 + q);
#pragma unroll
        for (int k = 0; k < 8; ++k) {
            plv[tid * 8 + k] = vals[k];
            pli[tid * 8 + k] = idxs[k];
        }
    }
    __syncthreads();

    // ---- merge + softmax + index output (1 thread per token) ----
    float g[8]; int fidx[8];
    const bool active = (tid < MB);
    if (active) {
        float vals[8]; int idxs[8];
#pragma unroll
        for (int k = 0; k < 8; ++k) { vals[k] = -FLT_MAX; idxs[k] = 0; }
        for (int p = 0; p < 8; ++p) {
#pragma unroll
            for (int k = 0; k < 8; ++k)
                insert8(vals, idxs, plv[(tid * 8 + p) * 8 + k], pli[(tid * 8 + p) * 8 + k]);
        }
        float mx = vals[0];
        float s = 0.0f;
#pragma unroll
        for (int k = 0; k < 8; ++k) { g[k] = __expf(vals[k] - mx); s += g[k]; }
        float inv = 1.0f / s;
#pragma unroll
        for (int k = 0; k < 8; ++k) { g[k] *= inv; fidx[k] = idxs[k]; }
        // indices written as float values (whole out buffer is read back as f32)
#pragma unroll
        for (int k = 0; k < 8; ++k)
            out_idx[(size_t)(tok0 + tid) * KTOP + k] = (float)idxs[k];
    }
    // zero dense gate rows (merge no longer reads lg)
    for (int f = tid; f < MB * 132; f += NTHR) lg[f] = 0.0f;
    __syncthreads();

    if (active) {
#pragma unroll
        for (int k = 0; k < 8; ++k) lg[tid * 132 + fidx[k]] = g[k];
    }
    __syncthreads();

    // ---- coalesced dense copy-out ----
    for (int f = tid; f < MB * (NEXP / 4); f += NTHR) {
        int m = f >> 5, e4 = f & 31;
        float4 v = *(const float4*)&lg[m * 132 + e4 * 4];
        ((float4*)out_gates)[(size_t)(tok0 + m) * (NEXP / 4) + e4] = v;
    }
}

extern "C" void kernel_launch(void* const* d_in, const int* in_sizes, int n_in,
                              void* d_out, int out_size, void* d_ws, size_t ws_size,
                              hipStream_t stream) {
    const float* x = (const float*)d_in[0];   // [B,N,D] f32
    const float* W = (const float*)d_in[1];   // [E,D]   f32
    const float* b = (const float*)d_in[2];   // [E]     f32

    float* out_gates = (float*)d_out;                       // [B,N,E] f32
    float* out_idx   = out_gates + (size_t)TOKENS * NEXP;   // [B,N,K] as f32

    uint4* wf = (uint4*)d_ws;   // 1 MB: W fp16 h/m fragment tables

    wfrag_kernel<<<dim3(WFRAG_N / 256), dim3(256), 0, stream>>>(W, wf);
    router_kernel<<<dim3(TOKENS / MB), dim3(NTHR), 0, stream>>>(x, wf, b, out_gates, out_idx);
}